// Round 1
// baseline (1255.342 us; speedup 1.0000x reference)
//
#include <hip/hip_runtime.h>

#define DEV __device__ __forceinline__

DEV float sigm(float x) { return 1.0f / (1.0f + __expf(-x)); }
DEV float tanhf_fast(float x) { return 1.0f - 2.0f / (1.0f + __expf(2.0f * x)); }

// ---------------------------------------------------------------------------
// Generic 2-segment GEMM: C[m,n] = act( A1[m,:K1]·W1[n,:K1] + A2[m,:K2]·W2[n,:K2]
//                                       + bias1[n] + bias2[n] ),  M = 128 fixed.
// W pointers may carry a column offset (ldw = true row stride). N % 32 == 0,
// K % 16 == 0. Grid = N/32 blocks, 256 threads.
// ---------------------------------------------------------------------------
__global__ __launch_bounds__(256) void gemm2_kernel(
    const float* __restrict__ A1, int K1, const float* __restrict__ W1, int ldw1,
    const float* __restrict__ A2, int K2, const float* __restrict__ W2, int ldw2,
    const float* __restrict__ bias1, const float* __restrict__ bias2,
    float* __restrict__ C, int N, int act)
{
    __shared__ float As[16][128];   // [k][m]
    __shared__ float Ws[16][33];    // [k][n], padded
    const int tid = threadIdx.x;
    const int n0 = blockIdx.x * 32;
    const int tx = tid & 15, ty = tid >> 4;
    const int lm = tid & 127, lk = (tid >> 7) * 8;

    float acc[16];
#pragma unroll
    for (int i = 0; i < 16; ++i) acc[i] = 0.f;

    for (int seg = 0; seg < 2; ++seg) {
        const float* A = seg ? A2 : A1;
        const float* W = seg ? W2 : W1;
        const int K = seg ? K2 : K1;
        const int ldw = seg ? ldw2 : ldw1;
        if (!A) continue;
        for (int k0 = 0; k0 < K; k0 += 16) {
            float4 a0 = *(const float4*)(A + lm * K + k0 + lk);
            float4 a1 = *(const float4*)(A + lm * K + k0 + lk + 4);
            As[lk + 0][lm] = a0.x; As[lk + 1][lm] = a0.y;
            As[lk + 2][lm] = a0.z; As[lk + 3][lm] = a0.w;
            As[lk + 4][lm] = a1.x; As[lk + 5][lm] = a1.y;
            As[lk + 6][lm] = a1.z; As[lk + 7][lm] = a1.w;
            if (tid < 128) {
                int nl = tid >> 2, kq = (tid & 3) * 4;
                float4 w = *(const float4*)(W + (n0 + nl) * ldw + k0 + kq);
                Ws[kq + 0][nl] = w.x; Ws[kq + 1][nl] = w.y;
                Ws[kq + 2][nl] = w.z; Ws[kq + 3][nl] = w.w;
            }
            __syncthreads();
#pragma unroll
            for (int kk = 0; kk < 16; ++kk) {
                float w0 = Ws[kk][tx * 2 + 0];
                float w1 = Ws[kk][tx * 2 + 1];
                float4 x0 = *(const float4*)&As[kk][ty * 8];
                float4 x1 = *(const float4*)&As[kk][ty * 8 + 4];
                acc[0] += x0.x * w0; acc[1] += x0.y * w0;
                acc[2] += x0.z * w0; acc[3] += x0.w * w0;
                acc[4] += x1.x * w0; acc[5] += x1.y * w0;
                acc[6] += x1.z * w0; acc[7] += x1.w * w0;
                acc[8]  += x0.x * w1; acc[9]  += x0.y * w1;
                acc[10] += x0.z * w1; acc[11] += x0.w * w1;
                acc[12] += x1.x * w1; acc[13] += x1.y * w1;
                acc[14] += x1.z * w1; acc[15] += x1.w * w1;
            }
            __syncthreads();
        }
    }
#pragma unroll
    for (int j = 0; j < 2; ++j) {
        int n = n0 + tx * 2 + j;
        float bb = (bias1 ? bias1[n] : 0.f) + (bias2 ? bias2[n] : 0.f);
#pragma unroll
        for (int i = 0; i < 8; ++i) {
            float v = acc[j * 8 + i] + bb;
            if (act == 1) v = tanhf_fast(v);
            C[(ty * 8 + i) * N + n] = v;
        }
    }
}

// ---------------------------------------------------------------------------
// GRU gate math: grid(128) x block(256);  D = 256
// ---------------------------------------------------------------------------
__global__ void gru_gate_kernel(const float* __restrict__ gi, const float* __restrict__ gh,
                                const float* __restrict__ h, float* __restrict__ out)
{
    int m = blockIdx.x, d = threadIdx.x;
    const float* gim = gi + m * 768;
    const float* ghm = gh + m * 768;
    float r = sigm(gim[d] + ghm[d]);
    float z = sigm(gim[256 + d] + ghm[256 + d]);
    float n = tanhf_fast(gim[512 + d] + r * ghm[512 + d]);
    out[m * 256 + d] = (1.f - z) * n + z * h[m * 256 + d];
}

// ---------------------------------------------------------------------------
// LSTM gate math: grid(ceil(H/256), 128);  optional residual accumulate
// ---------------------------------------------------------------------------
__global__ void lstm_gate_kernel(const float* __restrict__ g, const float* __restrict__ c_in,
                                 float* __restrict__ h_out, float* __restrict__ c_out,
                                 float* __restrict__ xacc, int H)
{
    int d = blockIdx.x * 256 + threadIdx.x;
    int m = blockIdx.y;
    if (d >= H) return;
    const float* gm = g + (size_t)m * 4 * H;
    float iv = gm[d], fv = gm[H + d], gv = gm[2 * H + d], ov = gm[3 * H + d];
    float c2 = sigm(fv) * c_in[m * H + d] + sigm(iv) * tanhf_fast(gv);
    float h2 = sigm(ov) * tanhf_fast(c2);
    h_out[m * H + d] = h2;
    c_out[m * H + d] = c2;
    if (xacc) xacc[m * H + d] += h2;
}

// ---------------------------------------------------------------------------
// L_w transpose: LwT[c][d] = L_w[d][c]   (8192 elems)
// ---------------------------------------------------------------------------
__global__ void transpose_lw_kernel(const float* __restrict__ Lw, float* __restrict__ LwT)
{
    int i = blockIdx.x * 256 + threadIdx.x;
    int c = i >> 8, d = i & 255;
    LwT[i] = Lw[d * 32 + c];
}

// ---------------------------------------------------------------------------
// Fused LSA u-kernel: conv(loc) + L-projection + tanh(pq+esp+ploc)·v -> sigmoid(u)
// grid(B*16) blocks (64 t's each), 256 threads.
// ---------------------------------------------------------------------------
__global__ __launch_bounds__(256) void attn_u_kernel(
    const float* __restrict__ esp, const float* __restrict__ pq,
    const float* __restrict__ LwT, const float* __restrict__ Lb,
    const float* __restrict__ vw, const float* __restrict__ cw,
    const float* __restrict__ cum, const float* __restrict__ prev,
    float* __restrict__ sig_out)
{
    const int b = blockIdx.x >> 4;
    const int t0 = (blockIdx.x & 15) << 6;
    const int tid = threadIdx.x;

    __shared__ float cum_s[96], prev_s[96];
    __shared__ float cw_s[2][32][33];
    __shared__ float conv_s[32][68];
    __shared__ float Lw_s[32][256];
    __shared__ float pq_s[256], vw_s[256];

    if (tid < 94) {
        int ti = t0 - 15 + tid;
        cum_s[tid] = (ti >= 0 && ti < 1024) ? cum[b * 1024 + ti] : 0.f;
    } else if (tid >= 128 && tid < 222) {
        int i = tid - 128;
        int ti = t0 - 15 + i;
        prev_s[i] = (ti >= 0 && ti < 1024) ? prev[b * 1024 + ti] : 0.f;
    }
    for (int i = tid; i < 2048; i += 256) {
        int which = i >> 10, c = (i >> 5) & 31, k = i & 31;
        cw_s[which][c][k] = (k < 31) ? cw[(c * 2 + which) * 31 + k] : 0.f;
    }
    for (int i = tid; i < 8192; i += 256)
        (&Lw_s[0][0])[i] = LwT[i];
    pq_s[tid] = pq[b * 256 + tid] + Lb[tid];
    vw_s[tid] = vw[tid];
    __syncthreads();

    // local conv: conv_s[c][t] for this 64-t tile
    {
        int c = tid & 31, t8 = (tid >> 5) << 3;
        float a[8] = {0.f, 0.f, 0.f, 0.f, 0.f, 0.f, 0.f, 0.f};
        for (int k = 0; k < 31; ++k) {
            float w0 = cw_s[0][c][k], w1 = cw_s[1][c][k];
#pragma unroll
            for (int j = 0; j < 8; ++j)
                a[j] += w0 * cum_s[t8 + j + k] + w1 * prev_s[t8 + j + k];
        }
#pragma unroll
        for (int j = 0; j < 8; ++j) conv_s[c][t8 + j] = a[j];
    }
    __syncthreads();

    // ploc accumulation: 8 t x 8 d per thread
    const int dg = (tid & 31) << 3;
    const int tg = (tid >> 5) << 3;
    float pl[8][8] = {};
#pragma unroll 4
    for (int c = 0; c < 32; ++c) {
        float4 lw0 = *(const float4*)&Lw_s[c][dg];
        float4 lw1 = *(const float4*)&Lw_s[c][dg + 4];
        float4 cv0 = *(const float4*)&conv_s[c][tg];
        float4 cv1 = *(const float4*)&conv_s[c][tg + 4];
        float lwv[8] = {lw0.x, lw0.y, lw0.z, lw0.w, lw1.x, lw1.y, lw1.z, lw1.w};
        float cvv[8] = {cv0.x, cv0.y, cv0.z, cv0.w, cv1.x, cv1.y, cv1.z, cv1.w};
#pragma unroll
        for (int jt = 0; jt < 8; ++jt)
#pragma unroll
            for (int jd = 0; jd < 8; ++jd)
                pl[jt][jd] += cvv[jt] * lwv[jd];
    }

    float4 pa = *(const float4*)&pq_s[dg];
    float4 pb = *(const float4*)&pq_s[dg + 4];
    float4 va = *(const float4*)&vw_s[dg];
    float4 vb = *(const float4*)&vw_s[dg + 4];
    float pqv[8] = {pa.x, pa.y, pa.z, pa.w, pb.x, pb.y, pb.z, pb.w};
    float vwv[8] = {va.x, va.y, va.z, va.w, vb.x, vb.y, vb.z, vb.w};

    float part[8];
#pragma unroll
    for (int jt = 0; jt < 8; ++jt) {
        int t = t0 + tg + jt;
        const float* er = esp + ((long)(b * 1024 + t) << 8) + dg;
        float4 e0 = *(const float4*)er;
        float4 e1 = *(const float4*)(er + 4);
        float ev[8] = {e0.x, e0.y, e0.z, e0.w, e1.x, e1.y, e1.z, e1.w};
        float s = 0.f;
#pragma unroll
        for (int jd = 0; jd < 8; ++jd)
            s += tanhf_fast(pqv[jd] + ev[jd] + pl[jt][jd]) * vwv[jd];
        part[jt] = s;
    }
#pragma unroll
    for (int off = 1; off < 32; off <<= 1)
#pragma unroll
        for (int jt = 0; jt < 8; ++jt)
            part[jt] += __shfl_xor(part[jt], off);
    if ((tid & 31) == 0) {
#pragma unroll
        for (int jt = 0; jt < 8; ++jt)
            sig_out[b * 1024 + t0 + tg + jt] = sigm(part[jt]);
    }
}

// ---------------------------------------------------------------------------
// Normalize: scores = sig / rowsum(sig), cum_new = cumulative + scores,
// and zero the context accumulator.  grid(128) x 256.
// ---------------------------------------------------------------------------
__global__ void attn_norm_kernel(const float* __restrict__ sig, const float* __restrict__ cum,
                                 float* __restrict__ scores, float* __restrict__ cum_new,
                                 float* __restrict__ ctx)
{
    __shared__ float red[4];
    int b = blockIdx.x, tid = threadIdx.x;
    float4 sv = *(const float4*)&sig[b * 1024 + tid * 4];
    float s = sv.x + sv.y + sv.z + sv.w;
#pragma unroll
    for (int off = 1; off < 64; off <<= 1) s += __shfl_xor(s, off);
    if ((tid & 63) == 0) red[tid >> 6] = s;
    __syncthreads();
    float inv = 1.f / (red[0] + red[1] + red[2] + red[3]);
    float4 cv = *(const float4*)&cum[b * 1024 + tid * 4];
    float4 sc = {sv.x * inv, sv.y * inv, sv.z * inv, sv.w * inv};
    *(float4*)&scores[b * 1024 + tid * 4] = sc;
    float4 cn = {cv.x + sc.x, cv.y + sc.y, cv.z + sc.z, cv.w + sc.w};
    *(float4*)&cum_new[b * 1024 + tid * 4] = cn;
    ctx[b * 256 + tid] = 0.f;
}

// ---------------------------------------------------------------------------
// context[b,d] = sum_t scores[b,t] * es[b,t,d];  grid(B*4) t-chunks of 256.
// ---------------------------------------------------------------------------
__global__ void attn_ctx_kernel(const float* __restrict__ scores, const float* __restrict__ es,
                                float* __restrict__ ctx)
{
    __shared__ float sc_s[256];
    int b = blockIdx.x >> 2;
    int tbase = (blockIdx.x & 3) * 256;
    int tid = threadIdx.x;
    sc_s[tid] = scores[b * 1024 + tbase + tid];
    __syncthreads();
    float a = 0.f;
    const float* ep = es + ((size_t)(b * 1024 + tbase)) * 256 + tid;
#pragma unroll 4
    for (int tt = 0; tt < 256; ++tt)
        a += sc_s[tt] * ep[(size_t)tt * 256];
    atomicAdd(&ctx[b * 256 + tid], a);
}

// ---------------------------------------------------------------------------
__global__ void build_rescat_kernel(const float* __restrict__ pre, const float* __restrict__ x,
                                    float* __restrict__ res)
{
    int idx = blockIdx.x * 256 + threadIdx.x;   // < 128*640
    int m = idx / 640, d = idx - m * 640;
    res[idx] = (d < 128) ? pre[m * 128 + d] : x[m * 512 + d - 128];
}

__global__ void copy_kernel(const float* __restrict__ src, float* __restrict__ dst, int n)
{
    int idx = blockIdx.x * 256 + threadIdx.x;
    if (idx < n) dst[idx] = src[idx];
}

__global__ void stop_kernel(const float* __restrict__ res, const float* __restrict__ sw,
                            const float* __restrict__ sb, float* __restrict__ stop)
{
    int m = blockIdx.x, lane = threadIdx.x;
    float s = 0.f;
    for (int k = lane; k < 640; k += 64) s += res[m * 640 + k] * sw[k];
#pragma unroll
    for (int off = 1; off < 64; off <<= 1) s += __shfl_xor(s, off);
    if (lane == 0) stop[m] = sigm(s + sb[0]);
}

// ---------------------------------------------------------------------------
extern "C" void kernel_launch(void* const* d_in, const int* in_sizes, int n_in,
                              void* d_out, int out_size, void* d_ws, size_t ws_size,
                              hipStream_t stream)
{
    const float* encoder_seq      = (const float*)d_in[0];
    const float* encoder_seq_proj = (const float*)d_in[1];
    const float* prenet_in        = (const float*)d_in[2];
    const float* attn_hidden      = (const float*)d_in[3];
    const float* rnn1_h  = (const float*)d_in[4];
    const float* rnn1_c  = (const float*)d_in[5];
    const float* rnn2_h  = (const float*)d_in[6];
    const float* rnn2_c  = (const float*)d_in[7];
    const float* res_h   = (const float*)d_in[8];
    const float* res_c   = (const float*)d_in[9];
    const float* context_vec = (const float*)d_in[10];
    const float* cumulative  = (const float*)d_in[11];
    const float* attn_prev   = (const float*)d_in[12];
    const float* fc1_w = (const float*)d_in[13];
    const float* fc1_b = (const float*)d_in[14];
    const float* fc2_w = (const float*)d_in[15];
    const float* fc2_b = (const float*)d_in[16];
    const float* gru_wih = (const float*)d_in[17];
    const float* gru_whh = (const float*)d_in[18];
    const float* gru_bih = (const float*)d_in[19];
    const float* gru_bhh = (const float*)d_in[20];
    const float* conv_w = (const float*)d_in[21];
    const float* L_w = (const float*)d_in[22];
    const float* L_b = (const float*)d_in[23];
    const float* W_w = (const float*)d_in[24];
    const float* W_b = (const float*)d_in[25];
    const float* v_w = (const float*)d_in[26];
    const float* ri_w = (const float*)d_in[27];
    const float* ri_b = (const float*)d_in[28];
    const float* r1_wih = (const float*)d_in[29];
    const float* r1_whh = (const float*)d_in[30];
    const float* r1_bih = (const float*)d_in[31];
    const float* r1_bhh = (const float*)d_in[32];
    const float* r2_wih = (const float*)d_in[33];
    const float* r2_whh = (const float*)d_in[34];
    const float* r2_bih = (const float*)d_in[35];
    const float* r2_bhh = (const float*)d_in[36];
    const float* res_wih = (const float*)d_in[37];
    const float* res_whh = (const float*)d_in[38];
    const float* res_bih = (const float*)d_in[39];
    const float* res_bhh = (const float*)d_in[40];
    const float* stop_w = (const float*)d_in[41];
    const float* stop_b = (const float*)d_in[42];

    float* ws  = (float*)d_ws;
    float* out = (float*)d_out;

    // workspace offsets (floats)
    const size_t OFF_P    = 0;        // [128,256]
    const size_t OFF_POUT = 32768;    // [128,128]
    const size_t OFF_GI   = 49152;    // [128,768]
    const size_t OFF_GH   = 147456;   // [128,768]
    const size_t OFF_PQ   = 245760;   // [128,256]
    const size_t OFF_SIG  = 278528;   // [128,1024]
    const size_t OFF_X    = 409600;   // [128,512]
    const size_t OFF_G    = 475136;   // [128,2560] max gate buffer
    const size_t OFF_RES  = 802816;   // [128,640]
    const size_t OFF_LWT  = 884736;   // [32,256]

    // output offsets (floats)
    const size_t O_COND   = 0;        // [128,640]
    const size_t O_STOP   = 81920;    // [128,1]
    const size_t O_SCORES = 82048;    // [128,1024]
    const size_t O_ATTNH  = 213120;   // [128,256]
    const size_t O_H1     = 245888;   // [128,512]
    const size_t O_C1     = 311424;
    const size_t O_H2     = 376960;
    const size_t O_C2     = 442496;
    const size_t O_HS     = 508032;   // [4,128,640]
    const size_t O_CS     = 835712;
    const size_t O_CTX    = 1163392;  // [128,256]
    const size_t O_CUM    = 1196160;  // [128,1024]

    // L_w transpose for coalesced LDS staging in attn_u
    transpose_lw_kernel<<<32, 256, 0, stream>>>(L_w, ws + OFF_LWT);

    // PreNet
    gemm2_kernel<<<8, 256, 0, stream>>>(prenet_in, 128, fc1_w, 128,
                                        nullptr, 0, nullptr, 0,
                                        fc1_b, nullptr, ws + OFF_P, 256, 1);
    gemm2_kernel<<<4, 256, 0, stream>>>(ws + OFF_P, 256, fc2_w, 256,
                                        nullptr, 0, nullptr, 0,
                                        fc2_b, nullptr, ws + OFF_POUT, 128, 1);

    // GRU: gi = [context_vec | prenet_out] @ gru_wih^T + bih ; gh = attn_hidden @ gru_whh^T + bhh
    gemm2_kernel<<<24, 256, 0, stream>>>(context_vec, 256, gru_wih, 384,
                                         ws + OFF_POUT, 128, gru_wih + 256, 384,
                                         gru_bih, nullptr, ws + OFF_GI, 768, 0);
    gemm2_kernel<<<24, 256, 0, stream>>>(attn_hidden, 256, gru_whh, 256,
                                         nullptr, 0, nullptr, 0,
                                         gru_bhh, nullptr, ws + OFF_GH, 768, 0);
    gru_gate_kernel<<<128, 256, 0, stream>>>(ws + OFF_GI, ws + OFF_GH, attn_hidden,
                                             out + O_ATTNH);

    // pq = attn_h @ W_w^T + W_b
    gemm2_kernel<<<8, 256, 0, stream>>>(out + O_ATTNH, 256, W_w, 256,
                                        nullptr, 0, nullptr, 0,
                                        W_b, nullptr, ws + OFF_PQ, 256, 0);

    // fused conv + L-proj + u + sigmoid
    attn_u_kernel<<<2048, 256, 0, stream>>>(encoder_seq_proj, ws + OFF_PQ, ws + OFF_LWT,
                                            L_b, v_w, conv_w, cumulative, attn_prev,
                                            ws + OFF_SIG);
    attn_norm_kernel<<<128, 256, 0, stream>>>(ws + OFF_SIG, cumulative,
                                              out + O_SCORES, out + O_CUM, out + O_CTX);
    attn_ctx_kernel<<<512, 256, 0, stream>>>(out + O_SCORES, encoder_seq, out + O_CTX);

    // x = [context | attn_h] @ ri_w^T + ri_b
    gemm2_kernel<<<16, 256, 0, stream>>>(out + O_CTX, 256, ri_w, 512,
                                         out + O_ATTNH, 256, ri_w + 256, 512,
                                         ri_b, nullptr, ws + OFF_X, 512, 0);

    // LSTM 1
    gemm2_kernel<<<64, 256, 0, stream>>>(ws + OFF_X, 512, r1_wih, 512,
                                         rnn1_h, 512, r1_whh, 512,
                                         r1_bih, r1_bhh, ws + OFF_G, 2048, 0);
    lstm_gate_kernel<<<dim3(2, 128), 256, 0, stream>>>(ws + OFF_G, rnn1_c,
                                                       out + O_H1, out + O_C1,
                                                       ws + OFF_X, 512);
    // LSTM 2
    gemm2_kernel<<<64, 256, 0, stream>>>(ws + OFF_X, 512, r2_wih, 512,
                                         rnn2_h, 512, r2_whh, 512,
                                         r2_bih, r2_bhh, ws + OFF_G, 2048, 0);
    lstm_gate_kernel<<<dim3(2, 128), 256, 0, stream>>>(ws + OFF_G, rnn2_c,
                                                       out + O_H2, out + O_C2,
                                                       ws + OFF_X, 512);

    // residual stack input
    build_rescat_kernel<<<320, 256, 0, stream>>>(prenet_in, ws + OFF_X, ws + OFF_RES);

    for (int i = 0; i < 4; ++i) {
        const float* wih = res_wih + (size_t)i * 2560 * 640;
        const float* whh = res_whh + (size_t)i * 2560 * 640;
        gemm2_kernel<<<80, 256, 0, stream>>>(ws + OFF_RES, 640, wih, 640,
                                             res_h + (size_t)i * 81920, 640, whh, 640,
                                             res_bih + (size_t)i * 2560,
                                             res_bhh + (size_t)i * 2560,
                                             ws + OFF_G, 2560, 0);
        lstm_gate_kernel<<<dim3(3, 128), 256, 0, stream>>>(ws + OFF_G,
                                                           res_c + (size_t)i * 81920,
                                                           out + O_HS + (size_t)i * 81920,
                                                           out + O_CS + (size_t)i * 81920,
                                                           ws + OFF_RES, 640);
    }

    // cond + stop
    copy_kernel<<<320, 256, 0, stream>>>(ws + OFF_RES, out + O_COND, 128 * 640);
    stop_kernel<<<128, 64, 0, stream>>>(ws + OFF_RES, stop_w, stop_b, out + O_STOP);
}

// Round 2
// 672.386 us; speedup vs baseline: 1.8670x; 1.8670x over previous
//
#include <hip/hip_runtime.h>

#define DEV __device__ __forceinline__

DEV float sigm(float x) { return 1.0f / (1.0f + __expf(-x)); }
DEV float tanhf_fast(float x) { return 1.0f - 2.0f / (1.0f + __expf(2.0f * x)); }

// ---------------------------------------------------------------------------
// Split-K 2-segment GEMM. Partial[chunk][m][n] = A1[m,:]·W1[n,:] ⊕ A2[m,:]·W2[n,:]
// restricted to combined-k range [chunk*KC, (chunk+1)*KC). No bias, no act.
// M = 128 fixed. N % 32 == 0, K1 % 16 == 0, KC % 16 == 0.
// Grid = (N/32) * KS blocks, 256 threads.
// ---------------------------------------------------------------------------
__global__ __launch_bounds__(256) void gemm2s_kernel(
    const float* __restrict__ A1, int K1, const float* __restrict__ W1, int ldw1,
    const float* __restrict__ A2, int K2, const float* __restrict__ W2, int ldw2,
    float* __restrict__ Cp, int N, int KS, int KC)
{
    __shared__ float As[16][128];   // [k][m]
    __shared__ float Ws[16][33];    // [k][n], padded
    const int tid = threadIdx.x;
    const int chunk = blockIdx.x % KS;
    const int n0 = (blockIdx.x / KS) * 32;
    const int kbeg = chunk * KC;
    const int kend = kbeg + KC;
    const int tx = tid & 15, ty = tid >> 4;
    const int lm = tid & 127, lk = (tid >> 7) * 8;

    float acc[16];
#pragma unroll
    for (int i = 0; i < 16; ++i) acc[i] = 0.f;

    for (int k0 = kbeg; k0 < kend; k0 += 16) {
        const float* A; const float* W; int lda, ldw, kc;
        if (k0 < K1) { A = A1; W = W1; lda = K1; ldw = ldw1; kc = k0; }
        else         { A = A2; W = W2; lda = K2; ldw = ldw2; kc = k0 - K1; }

        float4 a0 = *(const float4*)(A + (size_t)lm * lda + kc + lk);
        float4 a1 = *(const float4*)(A + (size_t)lm * lda + kc + lk + 4);
        As[lk + 0][lm] = a0.x; As[lk + 1][lm] = a0.y;
        As[lk + 2][lm] = a0.z; As[lk + 3][lm] = a0.w;
        As[lk + 4][lm] = a1.x; As[lk + 5][lm] = a1.y;
        As[lk + 6][lm] = a1.z; As[lk + 7][lm] = a1.w;
        if (tid < 128) {
            int nl = tid >> 2, kq = (tid & 3) * 4;
            float4 w = *(const float4*)(W + (size_t)(n0 + nl) * ldw + kc + kq);
            Ws[kq + 0][nl] = w.x; Ws[kq + 1][nl] = w.y;
            Ws[kq + 2][nl] = w.z; Ws[kq + 3][nl] = w.w;
        }
        __syncthreads();
#pragma unroll
        for (int kk = 0; kk < 16; ++kk) {
            float w0 = Ws[kk][tx * 2 + 0];
            float w1 = Ws[kk][tx * 2 + 1];
            float4 x0 = *(const float4*)&As[kk][ty * 8];
            float4 x1 = *(const float4*)&As[kk][ty * 8 + 4];
            acc[0] += x0.x * w0; acc[1] += x0.y * w0;
            acc[2] += x0.z * w0; acc[3] += x0.w * w0;
            acc[4] += x1.x * w0; acc[5] += x1.y * w0;
            acc[6] += x1.z * w0; acc[7] += x1.w * w0;
            acc[8]  += x0.x * w1; acc[9]  += x0.y * w1;
            acc[10] += x0.z * w1; acc[11] += x0.w * w1;
            acc[12] += x1.x * w1; acc[13] += x1.y * w1;
            acc[14] += x1.z * w1; acc[15] += x1.w * w1;
        }
        __syncthreads();
    }

    float* Co = Cp + (size_t)chunk * 128 * N;
#pragma unroll
    for (int j = 0; j < 2; ++j) {
        int n = n0 + tx * 2 + j;
#pragma unroll
        for (int i = 0; i < 8; ++i)
            Co[(size_t)(ty * 8 + i) * N + n] = acc[j * 8 + i];
    }
}

// ---------------------------------------------------------------------------
// reduce KS partials + bias, optional tanh.  grid(MN/256).
// ---------------------------------------------------------------------------
__global__ void reduce_act_kernel(const float* __restrict__ p, int KS, int MN,
                                  const float* __restrict__ b,
                                  float* __restrict__ out, int N, int act)
{
    int idx = blockIdx.x * 256 + threadIdx.x;
    if (idx >= MN) return;
    int n = idx % N;
    float v = b ? b[n] : 0.f;
    for (int s = 0; s < KS; ++s) v += p[(size_t)s * MN + idx];
    if (act) v = tanhf_fast(v);
    out[idx] = v;
}

// ---------------------------------------------------------------------------
// GRU gate math from split-K partials: grid(128) x 256;  D = 256, N = 768
// ---------------------------------------------------------------------------
__global__ void gru_gate_kernel(const float* __restrict__ gi_p, int KSi,
                                const float* __restrict__ gh_p, int KSh,
                                const float* __restrict__ bih, const float* __restrict__ bhh,
                                const float* __restrict__ h, float* __restrict__ out)
{
    const size_t MN = 128 * 768;
    int m = blockIdx.x, d = threadIdx.x;
    size_t base = (size_t)m * 768 + d;
    float ir = bih[d], iz = bih[256 + d], in = bih[512 + d];
    for (int s = 0; s < KSi; ++s) {
        const float* p = gi_p + s * MN + base;
        ir += p[0]; iz += p[256]; in += p[512];
    }
    float hr = bhh[d], hz = bhh[256 + d], hn = bhh[512 + d];
    for (int s = 0; s < KSh; ++s) {
        const float* p = gh_p + s * MN + base;
        hr += p[0]; hz += p[256]; hn += p[512];
    }
    float r = sigm(ir + hr);
    float z = sigm(iz + hz);
    float n = tanhf_fast(in + r * hn);
    out[m * 256 + d] = (1.f - z) * n + z * h[m * 256 + d];
}

// ---------------------------------------------------------------------------
// LSTM gate math from split-K partials: grid(ceil(H/256), 128)
// ---------------------------------------------------------------------------
__global__ void lstm_gate_kernel(const float* __restrict__ gp, int KS,
                                 const float* __restrict__ bih, const float* __restrict__ bhh,
                                 const float* __restrict__ c_in,
                                 float* __restrict__ h_out, float* __restrict__ c_out,
                                 float* __restrict__ xacc, int H)
{
    int d = blockIdx.x * 256 + threadIdx.x;
    int m = blockIdx.y;
    if (d >= H) return;
    const size_t MN = (size_t)128 * 4 * H;
    size_t base = (size_t)m * 4 * H + d;
    float iv = bih[d] + bhh[d];
    float fv = bih[H + d] + bhh[H + d];
    float gv = bih[2 * H + d] + bhh[2 * H + d];
    float ov = bih[3 * H + d] + bhh[3 * H + d];
    for (int s = 0; s < KS; ++s) {
        const float* p = gp + s * MN + base;
        iv += p[0]; fv += p[H]; gv += p[2 * H]; ov += p[3 * H];
    }
    float c2 = sigm(fv) * c_in[m * H + d] + sigm(iv) * tanhf_fast(gv);
    float h2 = sigm(ov) * tanhf_fast(c2);
    h_out[m * H + d] = h2;
    c_out[m * H + d] = c2;
    if (xacc) xacc[m * H + d] += h2;
}

// ---------------------------------------------------------------------------
__global__ void transpose_lw_kernel(const float* __restrict__ Lw, float* __restrict__ LwT)
{
    int i = blockIdx.x * 256 + threadIdx.x;
    int c = i >> 8, d = i & 255;
    LwT[i] = Lw[d * 32 + c];
}

// ---------------------------------------------------------------------------
// Fused LSA u-kernel: conv(loc) + L-projection + tanh(pq+esp+ploc)·v -> sigmoid(u)
// grid(B*16) blocks (64 t's each), 256 threads.
// ---------------------------------------------------------------------------
__global__ __launch_bounds__(256) void attn_u_kernel(
    const float* __restrict__ esp, const float* __restrict__ pq,
    const float* __restrict__ LwT, const float* __restrict__ Lb,
    const float* __restrict__ vw, const float* __restrict__ cw,
    const float* __restrict__ cum, const float* __restrict__ prev,
    float* __restrict__ sig_out)
{
    const int b = blockIdx.x >> 4;
    const int t0 = (blockIdx.x & 15) << 6;
    const int tid = threadIdx.x;

    __shared__ float cum_s[96], prev_s[96];
    __shared__ float cw_s[2][32][33];
    __shared__ float conv_s[32][68];
    __shared__ float Lw_s[32][256];
    __shared__ float pq_s[256], vw_s[256];

    if (tid < 94) {
        int ti = t0 - 15 + tid;
        cum_s[tid] = (ti >= 0 && ti < 1024) ? cum[b * 1024 + ti] : 0.f;
    } else if (tid >= 128 && tid < 222) {
        int i = tid - 128;
        int ti = t0 - 15 + i;
        prev_s[i] = (ti >= 0 && ti < 1024) ? prev[b * 1024 + ti] : 0.f;
    }
    for (int i = tid; i < 2048; i += 256) {
        int which = i >> 10, c = (i >> 5) & 31, k = i & 31;
        cw_s[which][c][k] = (k < 31) ? cw[(c * 2 + which) * 31 + k] : 0.f;
    }
    for (int i = tid; i < 8192; i += 256)
        (&Lw_s[0][0])[i] = LwT[i];
    pq_s[tid] = pq[b * 256 + tid] + Lb[tid];
    vw_s[tid] = vw[tid];
    __syncthreads();

    {
        int c = tid & 31, t8 = (tid >> 5) << 3;
        float a[8] = {0.f, 0.f, 0.f, 0.f, 0.f, 0.f, 0.f, 0.f};
        for (int k = 0; k < 31; ++k) {
            float w0 = cw_s[0][c][k], w1 = cw_s[1][c][k];
#pragma unroll
            for (int j = 0; j < 8; ++j)
                a[j] += w0 * cum_s[t8 + j + k] + w1 * prev_s[t8 + j + k];
        }
#pragma unroll
        for (int j = 0; j < 8; ++j) conv_s[c][t8 + j] = a[j];
    }
    __syncthreads();

    const int dg = (tid & 31) << 3;
    const int tg = (tid >> 5) << 3;
    float pl[8][8] = {};
#pragma unroll 4
    for (int c = 0; c < 32; ++c) {
        float4 lw0 = *(const float4*)&Lw_s[c][dg];
        float4 lw1 = *(const float4*)&Lw_s[c][dg + 4];
        float4 cv0 = *(const float4*)&conv_s[c][tg];
        float4 cv1 = *(const float4*)&conv_s[c][tg + 4];
        float lwv[8] = {lw0.x, lw0.y, lw0.z, lw0.w, lw1.x, lw1.y, lw1.z, lw1.w};
        float cvv[8] = {cv0.x, cv0.y, cv0.z, cv0.w, cv1.x, cv1.y, cv1.z, cv1.w};
#pragma unroll
        for (int jt = 0; jt < 8; ++jt)
#pragma unroll
            for (int jd = 0; jd < 8; ++jd)
                pl[jt][jd] += cvv[jt] * lwv[jd];
    }

    float4 pa = *(const float4*)&pq_s[dg];
    float4 pb = *(const float4*)&pq_s[dg + 4];
    float4 va = *(const float4*)&vw_s[dg];
    float4 vb = *(const float4*)&vw_s[dg + 4];
    float pqv[8] = {pa.x, pa.y, pa.z, pa.w, pb.x, pb.y, pb.z, pb.w};
    float vwv[8] = {va.x, va.y, va.z, va.w, vb.x, vb.y, vb.z, vb.w};

    float part[8];
#pragma unroll
    for (int jt = 0; jt < 8; ++jt) {
        int t = t0 + tg + jt;
        const float* er = esp + ((long)(b * 1024 + t) << 8) + dg;
        float4 e0 = *(const float4*)er;
        float4 e1 = *(const float4*)(er + 4);
        float ev[8] = {e0.x, e0.y, e0.z, e0.w, e1.x, e1.y, e1.z, e1.w};
        float s = 0.f;
#pragma unroll
        for (int jd = 0; jd < 8; ++jd)
            s += tanhf_fast(pqv[jd] + ev[jd] + pl[jt][jd]) * vwv[jd];
        part[jt] = s;
    }
#pragma unroll
    for (int off = 1; off < 32; off <<= 1)
#pragma unroll
        for (int jt = 0; jt < 8; ++jt)
            part[jt] += __shfl_xor(part[jt], off);
    if ((tid & 31) == 0) {
#pragma unroll
        for (int jt = 0; jt < 8; ++jt)
            sig_out[b * 1024 + t0 + tg + jt] = sigm(part[jt]);
    }
}

// ---------------------------------------------------------------------------
__global__ void attn_norm_kernel(const float* __restrict__ sig, const float* __restrict__ cum,
                                 float* __restrict__ scores, float* __restrict__ cum_new,
                                 float* __restrict__ ctx)
{
    __shared__ float red[4];
    int b = blockIdx.x, tid = threadIdx.x;
    float4 sv = *(const float4*)&sig[b * 1024 + tid * 4];
    float s = sv.x + sv.y + sv.z + sv.w;
#pragma unroll
    for (int off = 1; off < 64; off <<= 1) s += __shfl_xor(s, off);
    if ((tid & 63) == 0) red[tid >> 6] = s;
    __syncthreads();
    float inv = 1.f / (red[0] + red[1] + red[2] + red[3]);
    float4 cv = *(const float4*)&cum[b * 1024 + tid * 4];
    float4 sc = {sv.x * inv, sv.y * inv, sv.z * inv, sv.w * inv};
    *(float4*)&scores[b * 1024 + tid * 4] = sc;
    float4 cn = {cv.x + sc.x, cv.y + sc.y, cv.z + sc.z, cv.w + sc.w};
    *(float4*)&cum_new[b * 1024 + tid * 4] = cn;
    ctx[b * 256 + tid] = 0.f;
}

// ---------------------------------------------------------------------------
__global__ void attn_ctx_kernel(const float* __restrict__ scores, const float* __restrict__ es,
                                float* __restrict__ ctx)
{
    __shared__ float sc_s[256];
    int b = blockIdx.x >> 2;
    int tbase = (blockIdx.x & 3) * 256;
    int tid = threadIdx.x;
    sc_s[tid] = scores[b * 1024 + tbase + tid];
    __syncthreads();
    float a = 0.f;
    const float* ep = es + ((size_t)(b * 1024 + tbase)) * 256 + tid;
#pragma unroll 4
    for (int tt = 0; tt < 256; ++tt)
        a += sc_s[tt] * ep[(size_t)tt * 256];
    atomicAdd(&ctx[b * 256 + tid], a);
}

// ---------------------------------------------------------------------------
__global__ void build_rescat_kernel(const float* __restrict__ pre, const float* __restrict__ x,
                                    float* __restrict__ res)
{
    int idx = blockIdx.x * 256 + threadIdx.x;   // < 128*640
    int m = idx / 640, d = idx - m * 640;
    res[idx] = (d < 128) ? pre[m * 128 + d] : x[m * 512 + d - 128];
}

__global__ void copy_kernel(const float* __restrict__ src, float* __restrict__ dst, int n)
{
    int idx = blockIdx.x * 256 + threadIdx.x;
    if (idx < n) dst[idx] = src[idx];
}

__global__ void stop_kernel(const float* __restrict__ res, const float* __restrict__ sw,
                            const float* __restrict__ sb, float* __restrict__ stop)
{
    int m = blockIdx.x, lane = threadIdx.x;
    float s = 0.f;
    for (int k = lane; k < 640; k += 64) s += res[m * 640 + k] * sw[k];
#pragma unroll
    for (int off = 1; off < 64; off <<= 1) s += __shfl_xor(s, off);
    if (lane == 0) stop[m] = sigm(s + sb[0]);
}

// ---------------------------------------------------------------------------
extern "C" void kernel_launch(void* const* d_in, const int* in_sizes, int n_in,
                              void* d_out, int out_size, void* d_ws, size_t ws_size,
                              hipStream_t stream)
{
    const float* encoder_seq      = (const float*)d_in[0];
    const float* encoder_seq_proj = (const float*)d_in[1];
    const float* prenet_in        = (const float*)d_in[2];
    const float* attn_hidden      = (const float*)d_in[3];
    const float* rnn1_h  = (const float*)d_in[4];
    const float* rnn1_c  = (const float*)d_in[5];
    const float* rnn2_h  = (const float*)d_in[6];
    const float* rnn2_c  = (const float*)d_in[7];
    const float* res_h   = (const float*)d_in[8];
    const float* res_c   = (const float*)d_in[9];
    const float* context_vec = (const float*)d_in[10];
    const float* cumulative  = (const float*)d_in[11];
    const float* attn_prev   = (const float*)d_in[12];
    const float* fc1_w = (const float*)d_in[13];
    const float* fc1_b = (const float*)d_in[14];
    const float* fc2_w = (const float*)d_in[15];
    const float* fc2_b = (const float*)d_in[16];
    const float* gru_wih = (const float*)d_in[17];
    const float* gru_whh = (const float*)d_in[18];
    const float* gru_bih = (const float*)d_in[19];
    const float* gru_bhh = (const float*)d_in[20];
    const float* conv_w = (const float*)d_in[21];
    const float* L_w = (const float*)d_in[22];
    const float* L_b = (const float*)d_in[23];
    const float* W_w = (const float*)d_in[24];
    const float* W_b = (const float*)d_in[25];
    const float* v_w = (const float*)d_in[26];
    const float* ri_w = (const float*)d_in[27];
    const float* ri_b = (const float*)d_in[28];
    const float* r1_wih = (const float*)d_in[29];
    const float* r1_whh = (const float*)d_in[30];
    const float* r1_bih = (const float*)d_in[31];
    const float* r1_bhh = (const float*)d_in[32];
    const float* r2_wih = (const float*)d_in[33];
    const float* r2_whh = (const float*)d_in[34];
    const float* r2_bih = (const float*)d_in[35];
    const float* r2_bhh = (const float*)d_in[36];
    const float* res_wih = (const float*)d_in[37];
    const float* res_whh = (const float*)d_in[38];
    const float* res_bih = (const float*)d_in[39];
    const float* res_bhh = (const float*)d_in[40];
    const float* stop_w = (const float*)d_in[41];
    const float* stop_b = (const float*)d_in[42];

    float* ws  = (float*)d_ws;
    float* out = (float*)d_out;

    // workspace offsets (floats)
    const size_t OFF_P    = 0;        // [128,256]
    const size_t OFF_POUT = 32768;    // [128,128]
    const size_t OFF_PQ   = 49152;    // [128,256]
    const size_t OFF_SIG  = 81920;    // [128,1024]
    const size_t OFF_X    = 212992;   // [128,512]
    const size_t OFF_RES  = 278528;   // [128,640]
    const size_t OFF_LWT  = 360448;   // [32,256]
    const size_t OFF_PART = 368640;   // split-K partials, up to 8*128*2560 floats (10.5 MB)
    const size_t OFF_PARTB = OFF_PART + (size_t)8 * 128 * 768;  // second region for GRU gh

    // output offsets (floats)
    const size_t O_COND   = 0;
    const size_t O_STOP   = 81920;
    const size_t O_SCORES = 82048;
    const size_t O_ATTNH  = 213120;
    const size_t O_H1     = 245888;
    const size_t O_C1     = 311424;
    const size_t O_H2     = 376960;
    const size_t O_C2     = 442496;
    const size_t O_HS     = 508032;
    const size_t O_CS     = 835712;
    const size_t O_CTX    = 1163392;
    const size_t O_CUM    = 1196160;

    transpose_lw_kernel<<<32, 256, 0, stream>>>(L_w, ws + OFF_LWT);

    // PreNet fc1: N=256, K=128, KS=4 (KC=32)
    gemm2s_kernel<<<8 * 4, 256, 0, stream>>>(prenet_in, 128, fc1_w, 128,
                                             nullptr, 0, nullptr, 0,
                                             ws + OFF_PART, 256, 4, 32);
    reduce_act_kernel<<<128, 256, 0, stream>>>(ws + OFF_PART, 4, 128 * 256, fc1_b,
                                               ws + OFF_P, 256, 1);
    // PreNet fc2: N=128, K=256, KS=8 (KC=32)
    gemm2s_kernel<<<4 * 8, 256, 0, stream>>>(ws + OFF_P, 256, fc2_w, 256,
                                             nullptr, 0, nullptr, 0,
                                             ws + OFF_PART, 128, 8, 32);
    reduce_act_kernel<<<64, 256, 0, stream>>>(ws + OFF_PART, 8, 128 * 128, fc2_b,
                                              ws + OFF_POUT, 128, 1);

    // GRU gi: N=768, K=256+128, KS=8 (KC=48);  gh: N=768, K=256, KS=8 (KC=32)
    gemm2s_kernel<<<24 * 8, 256, 0, stream>>>(context_vec, 256, gru_wih, 384,
                                              ws + OFF_POUT, 128, gru_wih + 256, 384,
                                              ws + OFF_PART, 768, 8, 48);
    gemm2s_kernel<<<24 * 8, 256, 0, stream>>>(attn_hidden, 256, gru_whh, 256,
                                              nullptr, 0, nullptr, 0,
                                              ws + OFF_PARTB, 768, 8, 32);
    gru_gate_kernel<<<128, 256, 0, stream>>>(ws + OFF_PART, 8, ws + OFF_PARTB, 8,
                                             gru_bih, gru_bhh, attn_hidden, out + O_ATTNH);

    // pq: N=256, K=256, KS=8 (KC=32)
    gemm2s_kernel<<<8 * 8, 256, 0, stream>>>(out + O_ATTNH, 256, W_w, 256,
                                             nullptr, 0, nullptr, 0,
                                             ws + OFF_PART, 256, 8, 32);
    reduce_act_kernel<<<128, 256, 0, stream>>>(ws + OFF_PART, 8, 128 * 256, W_b,
                                               ws + OFF_PQ, 256, 0);

    attn_u_kernel<<<2048, 256, 0, stream>>>(encoder_seq_proj, ws + OFF_PQ, ws + OFF_LWT,
                                            L_b, v_w, conv_w, cumulative, attn_prev,
                                            ws + OFF_SIG);
    attn_norm_kernel<<<128, 256, 0, stream>>>(ws + OFF_SIG, cumulative,
                                              out + O_SCORES, out + O_CUM, out + O_CTX);
    attn_ctx_kernel<<<512, 256, 0, stream>>>(out + O_SCORES, encoder_seq, out + O_CTX);

    // x = [context | attn_h] @ ri_w^T + ri_b : N=512, K=512, KS=8 (KC=64)
    gemm2s_kernel<<<16 * 8, 256, 0, stream>>>(out + O_CTX, 256, ri_w, 512,
                                              out + O_ATTNH, 256, ri_w + 256, 512,
                                              ws + OFF_PART, 512, 8, 64);
    reduce_act_kernel<<<256, 256, 0, stream>>>(ws + OFF_PART, 8, 128 * 512, ri_b,
                                               ws + OFF_X, 512, 0);

    // LSTM 1: N=2048, K=1024, KS=8 (KC=128)
    gemm2s_kernel<<<64 * 8, 256, 0, stream>>>(ws + OFF_X, 512, r1_wih, 512,
                                              rnn1_h, 512, r1_whh, 512,
                                              ws + OFF_PART, 2048, 8, 128);
    lstm_gate_kernel<<<dim3(2, 128), 256, 0, stream>>>(ws + OFF_PART, 8, r1_bih, r1_bhh,
                                                       rnn1_c, out + O_H1, out + O_C1,
                                                       ws + OFF_X, 512);
    // LSTM 2
    gemm2s_kernel<<<64 * 8, 256, 0, stream>>>(ws + OFF_X, 512, r2_wih, 512,
                                              rnn2_h, 512, r2_whh, 512,
                                              ws + OFF_PART, 2048, 8, 128);
    lstm_gate_kernel<<<dim3(2, 128), 256, 0, stream>>>(ws + OFF_PART, 8, r2_bih, r2_bhh,
                                                       rnn2_c, out + O_H2, out + O_C2,
                                                       ws + OFF_X, 512);

    build_rescat_kernel<<<320, 256, 0, stream>>>(prenet_in, ws + OFF_X, ws + OFF_RES);

    // Residual stack: N=2560, K=1280, KS=8 (KC=160)
    for (int i = 0; i < 4; ++i) {
        const float* wih = res_wih + (size_t)i * 2560 * 640;
        const float* whh = res_whh + (size_t)i * 2560 * 640;
        gemm2s_kernel<<<80 * 8, 256, 0, stream>>>(ws + OFF_RES, 640, wih, 640,
                                                  res_h + (size_t)i * 81920, 640, whh, 640,
                                                  ws + OFF_PART, 2560, 8, 160);
        lstm_gate_kernel<<<dim3(3, 128), 256, 0, stream>>>(ws + OFF_PART, 8,
                                                           res_bih + (size_t)i * 2560,
                                                           res_bhh + (size_t)i * 2560,
                                                           res_c + (size_t)i * 81920,
                                                           out + O_HS + (size_t)i * 81920,
                                                           out + O_CS + (size_t)i * 81920,
                                                           ws + OFF_RES, 640);
    }

    copy_kernel<<<320, 256, 0, stream>>>(ws + OFF_RES, out + O_COND, 128 * 640);
    stop_kernel<<<128, 64, 0, stream>>>(ws + OFF_RES, stop_w, stop_b, out + O_STOP);
}

// Round 3
// 660.336 us; speedup vs baseline: 1.9011x; 1.0182x over previous
//
#include <hip/hip_runtime.h>

#define DEV __device__ __forceinline__

typedef __attribute__((ext_vector_type(8))) short short8;
typedef __attribute__((ext_vector_type(4))) float f32x4;

DEV float fast_rcp(float x) { return __builtin_amdgcn_rcpf(x); }
DEV float sigm(float x) { return fast_rcp(1.0f + __expf(-x)); }
DEV float tanhf_fast(float x) { return 1.0f - 2.0f * fast_rcp(1.0f + __expf(2.0f * x)); }

DEV short f2bf(float f) {
    unsigned u = __float_as_uint(f);
    unsigned r = (u + 0x7FFFu + ((u >> 16) & 1u)) >> 16;
    return (short)r;
}

// ---------------------------------------------------------------------------
// Split-K 2-segment GEMM, double-buffered LDS.
// Partial[chunk][m][n]; M = 128, N % 32 == 0, K1 % 16 == 0, KC % 16 == 0.
// Grid = (N/32) * KS blocks, 256 threads.
// ---------------------------------------------------------------------------
__global__ __launch_bounds__(256) void gemm2s_kernel(
    const float* __restrict__ A1, int K1, const float* __restrict__ W1, int ldw1,
    const float* __restrict__ A2, int K2, const float* __restrict__ W2, int ldw2,
    float* __restrict__ Cp, int N, int KS, int KC)
{
    __shared__ float As[2][16][128];   // [buf][k][m]
    __shared__ float Ws[2][16][33];    // [buf][k][n], padded
    const int tid = threadIdx.x;
    const int chunk = blockIdx.x % KS;
    const int n0 = (blockIdx.x / KS) * 32;
    const int kbeg = chunk * KC;
    const int nt = KC / 16;
    const int tx = tid & 15, ty = tid >> 4;
    const int lm = tid & 127, lk = (tid >> 7) * 8;

    float acc[16];
#pragma unroll
    for (int i = 0; i < 16; ++i) acc[i] = 0.f;

    float4 ra0, ra1, rw;
    auto load_regs = [&](int k0) {
        const float* A; const float* W; int lda, ldw, kc;
        if (k0 < K1) { A = A1; W = W1; lda = K1; ldw = ldw1; kc = k0; }
        else         { A = A2; W = W2; lda = K2; ldw = ldw2; kc = k0 - K1; }
        ra0 = *(const float4*)(A + (size_t)lm * lda + kc + lk);
        ra1 = *(const float4*)(A + (size_t)lm * lda + kc + lk + 4);
        if (tid < 128) {
            int nl = tid >> 2, kq = (tid & 3) * 4;
            rw = *(const float4*)(W + (size_t)(n0 + nl) * ldw + kc + kq);
        }
    };
    auto store_lds = [&](int buf) {
        As[buf][lk + 0][lm] = ra0.x; As[buf][lk + 1][lm] = ra0.y;
        As[buf][lk + 2][lm] = ra0.z; As[buf][lk + 3][lm] = ra0.w;
        As[buf][lk + 4][lm] = ra1.x; As[buf][lk + 5][lm] = ra1.y;
        As[buf][lk + 6][lm] = ra1.z; As[buf][lk + 7][lm] = ra1.w;
        if (tid < 128) {
            int nl = tid >> 2, kq = (tid & 3) * 4;
            Ws[buf][kq + 0][nl] = rw.x; Ws[buf][kq + 1][nl] = rw.y;
            Ws[buf][kq + 2][nl] = rw.z; Ws[buf][kq + 3][nl] = rw.w;
        }
    };

    load_regs(kbeg);
    store_lds(0);
    __syncthreads();

    for (int it = 0; it < nt; ++it) {
        const int cur = it & 1;
        if (it + 1 < nt) load_regs(kbeg + (it + 1) * 16);
#pragma unroll
        for (int kk = 0; kk < 16; ++kk) {
            float w0 = Ws[cur][kk][tx * 2 + 0];
            float w1 = Ws[cur][kk][tx * 2 + 1];
            float4 x0 = *(const float4*)&As[cur][kk][ty * 8];
            float4 x1 = *(const float4*)&As[cur][kk][ty * 8 + 4];
            acc[0] += x0.x * w0; acc[1] += x0.y * w0;
            acc[2] += x0.z * w0; acc[3] += x0.w * w0;
            acc[4] += x1.x * w0; acc[5] += x1.y * w0;
            acc[6] += x1.z * w0; acc[7] += x1.w * w0;
            acc[8]  += x0.x * w1; acc[9]  += x0.y * w1;
            acc[10] += x0.z * w1; acc[11] += x0.w * w1;
            acc[12] += x1.x * w1; acc[13] += x1.y * w1;
            acc[14] += x1.z * w1; acc[15] += x1.w * w1;
        }
        if (it + 1 < nt) store_lds(cur ^ 1);
        __syncthreads();
    }

    float* Co = Cp + (size_t)chunk * 128 * N;
#pragma unroll
    for (int j = 0; j < 2; ++j) {
        int n = n0 + tx * 2 + j;
#pragma unroll
        for (int i = 0; i < 8; ++i)
            Co[(size_t)(ty * 8 + i) * N + n] = acc[j * 8 + i];
    }
}

// ---------------------------------------------------------------------------
__global__ void reduce_act_kernel(const float* __restrict__ p, int KS, int MN,
                                  const float* __restrict__ b,
                                  float* __restrict__ out, int N, int act)
{
    int idx = blockIdx.x * 256 + threadIdx.x;
    if (idx >= MN) return;
    int n = idx % N;
    float v = b ? b[n] : 0.f;
    for (int s = 0; s < KS; ++s) v += p[(size_t)s * MN + idx];
    if (act) v = tanhf_fast(v);
    out[idx] = v;
}

// ---------------------------------------------------------------------------
__global__ void gru_gate_kernel(const float* __restrict__ gi_p, int KSi,
                                const float* __restrict__ gh_p, int KSh,
                                const float* __restrict__ bih, const float* __restrict__ bhh,
                                const float* __restrict__ h, float* __restrict__ out)
{
    const size_t MN = 128 * 768;
    int m = blockIdx.x, d = threadIdx.x;
    size_t base = (size_t)m * 768 + d;
    float ir = bih[d], iz = bih[256 + d], in = bih[512 + d];
    for (int s = 0; s < KSi; ++s) {
        const float* p = gi_p + s * MN + base;
        ir += p[0]; iz += p[256]; in += p[512];
    }
    float hr = bhh[d], hz = bhh[256 + d], hn = bhh[512 + d];
    for (int s = 0; s < KSh; ++s) {
        const float* p = gh_p + s * MN + base;
        hr += p[0]; hz += p[256]; hn += p[512];
    }
    float r = sigm(ir + hr);
    float z = sigm(iz + hz);
    float n = tanhf_fast(in + r * hn);
    out[m * 256 + d] = (1.f - z) * n + z * h[m * 256 + d];
}

// ---------------------------------------------------------------------------
__global__ void lstm_gate_kernel(const float* __restrict__ gp, int KS,
                                 const float* __restrict__ bih, const float* __restrict__ bhh,
                                 const float* __restrict__ c_in,
                                 float* __restrict__ h_out, float* __restrict__ c_out,
                                 float* __restrict__ xacc, int H)
{
    int d = blockIdx.x * 256 + threadIdx.x;
    int m = blockIdx.y;
    if (d >= H) return;
    const size_t MN = (size_t)128 * 4 * H;
    size_t base = (size_t)m * 4 * H + d;
    float iv = bih[d] + bhh[d];
    float fv = bih[H + d] + bhh[H + d];
    float gv = bih[2 * H + d] + bhh[2 * H + d];
    float ov = bih[3 * H + d] + bhh[3 * H + d];
    for (int s = 0; s < KS; ++s) {
        const float* p = gp + s * MN + base;
        iv += p[0]; fv += p[H]; gv += p[2 * H]; ov += p[3 * H];
    }
    float c2 = sigm(fv) * c_in[m * H + d] + sigm(iv) * tanhf_fast(gv);
    float h2 = sigm(ov) * tanhf_fast(c2);
    h_out[m * H + d] = h2;
    c_out[m * H + d] = c2;
    if (xacc) xacc[m * H + d] += h2;
}

// ---------------------------------------------------------------------------
// L_w -> bf16 (row-major [d=256][c=32], same layout as source).  8192 elems.
// ---------------------------------------------------------------------------
__global__ void lw_bf16_kernel(const float* __restrict__ Lw, short* __restrict__ LwBf)
{
    int i = blockIdx.x * 256 + threadIdx.x;
    LwBf[i] = f2bf(Lw[i]);
}

// ---------------------------------------------------------------------------
// Fused LSA u-kernel: conv(loc) -> bf16 MFMA L-projection -> tanh -> v-dot ->
// sigmoid(u).  grid(B*16) blocks (64 t's each), 256 threads (4 waves).
// Wave w handles t-tile [t0+16w, t0+16w+16); per wave 16 MFMA (d-tiles).
// ---------------------------------------------------------------------------
__global__ __launch_bounds__(256) void attn_u_kernel(
    const float* __restrict__ esp, const float* __restrict__ pq,
    const short* __restrict__ LwBf, const float* __restrict__ Lb,
    const float* __restrict__ vw, const float* __restrict__ cw,
    const float* __restrict__ cum, const float* __restrict__ prev,
    float* __restrict__ sig_out)
{
    const int b = blockIdx.x >> 4;
    const int t0 = (blockIdx.x & 15) << 6;
    const int tid = threadIdx.x;

    __shared__ float cum_s[94], prev_s[94];
    __shared__ float cw_s[2][32][33];          // padded: conflict-free conv reads
    __shared__ short conv_bf[64 * 32];          // [t][c] bf16
    __shared__ short lw_bf[256 * 32];           // [d][c] bf16
    __shared__ float pq_s[256], vw_s[256];

    // ---- stage ----
    if (tid < 94) {
        int ti = t0 - 15 + tid;
        cum_s[tid] = (ti >= 0 && ti < 1024) ? cum[b * 1024 + ti] : 0.f;
    } else if (tid >= 128 && tid < 222) {
        int i = tid - 128;
        int ti = t0 - 15 + i;
        prev_s[i] = (ti >= 0 && ti < 1024) ? prev[b * 1024 + ti] : 0.f;
    }
    for (int i = tid; i < 2048; i += 256) {
        int which = i >> 10, c = (i >> 5) & 31, k = i & 31;
        cw_s[which][c][k] = (k < 31) ? cw[(c * 2 + which) * 31 + k] : 0.f;
    }
    {   // 16 KB linear copy of Lw (bf16)
        const int4* src = (const int4*)LwBf;
        int4* dst = (int4*)lw_bf;
#pragma unroll
        for (int k = 0; k < 4; ++k) dst[tid + k * 256] = src[tid + k * 256];
    }
    pq_s[tid] = pq[b * 256 + tid] + Lb[tid];
    vw_s[tid] = vw[tid];
    __syncthreads();

    // ---- conv: thread (c = tid&31, t-oct = tid>>5) ----
    {
        int c = tid & 31, t8 = (tid >> 5) << 3;
        float a[8] = {0.f, 0.f, 0.f, 0.f, 0.f, 0.f, 0.f, 0.f};
        for (int k = 0; k < 31; ++k) {
            float w0 = cw_s[0][c][k], w1 = cw_s[1][c][k];
#pragma unroll
            for (int j = 0; j < 8; ++j)
                a[j] += w0 * cum_s[t8 + j + k] + w1 * prev_s[t8 + j + k];
        }
#pragma unroll
        for (int j = 0; j < 8; ++j) conv_bf[(t8 + j) * 32 + c] = f2bf(a[j]);
    }
    __syncthreads();

    // ---- MFMA ploc + fused tanh/v-dot ----
    const int lane = tid & 63, w = tid >> 6;
    const int q = lane >> 4, c16 = lane & 15;
    const int myt = t0 + w * 16 + c16;

    short8 bfrag = *(const short8*)&conv_bf[(w * 16 + c16) * 32 + q * 8];
    const float* er = esp + ((size_t)(b * 1024 + myt) << 8);

    float s = 0.f;
#pragma unroll
    for (int dt = 0; dt < 16; ++dt) {
        short8 afrag = *(const short8*)&lw_bf[(dt * 16 + c16) * 32 + q * 8];
        f32x4 acc = {0.f, 0.f, 0.f, 0.f};
        acc = __builtin_amdgcn_mfma_f32_16x16x32_bf16(afrag, bfrag, acc, 0, 0, 0);
        const int d0 = dt * 16 + q * 4;
        float4 e   = *(const float4*)(er + d0);
        float4 pqv = *(const float4*)&pq_s[d0];
        float4 vwv = *(const float4*)&vw_s[d0];
        s += tanhf_fast(pqv.x + e.x + acc[0]) * vwv.x;
        s += tanhf_fast(pqv.y + e.y + acc[1]) * vwv.y;
        s += tanhf_fast(pqv.z + e.z + acc[2]) * vwv.z;
        s += tanhf_fast(pqv.w + e.w + acc[3]) * vwv.w;
    }
    s += __shfl_xor(s, 16);
    s += __shfl_xor(s, 32);
    if (lane < 16)
        sig_out[b * 1024 + t0 + w * 16 + lane] = sigm(s);
}

// ---------------------------------------------------------------------------
__global__ void attn_norm_kernel(const float* __restrict__ sig, const float* __restrict__ cum,
                                 float* __restrict__ scores, float* __restrict__ cum_new,
                                 float* __restrict__ ctx)
{
    __shared__ float red[4];
    int b = blockIdx.x, tid = threadIdx.x;
    float4 sv = *(const float4*)&sig[b * 1024 + tid * 4];
    float s = sv.x + sv.y + sv.z + sv.w;
#pragma unroll
    for (int off = 1; off < 64; off <<= 1) s += __shfl_xor(s, off);
    if ((tid & 63) == 0) red[tid >> 6] = s;
    __syncthreads();
    float inv = fast_rcp(red[0] + red[1] + red[2] + red[3]);
    float4 cv = *(const float4*)&cum[b * 1024 + tid * 4];
    float4 sc = {sv.x * inv, sv.y * inv, sv.z * inv, sv.w * inv};
    *(float4*)&scores[b * 1024 + tid * 4] = sc;
    float4 cn = {cv.x + sc.x, cv.y + sc.y, cv.z + sc.z, cv.w + sc.w};
    *(float4*)&cum_new[b * 1024 + tid * 4] = cn;
    ctx[b * 256 + tid] = 0.f;
}

// ---------------------------------------------------------------------------
// context[b,d] = sum_t scores[b,t] * es[b,t,d];  grid(B*8) t-chunks of 128.
// ---------------------------------------------------------------------------
__global__ void attn_ctx_kernel(const float* __restrict__ scores, const float* __restrict__ es,
                                float* __restrict__ ctx)
{
    __shared__ float sc_s[128];
    int b = blockIdx.x >> 3;
    int tbase = (blockIdx.x & 7) * 128;
    int tid = threadIdx.x;
    if (tid < 128) sc_s[tid] = scores[b * 1024 + tbase + tid];
    __syncthreads();
    float a = 0.f;
    const float* ep = es + ((size_t)(b * 1024 + tbase)) * 256 + tid;
#pragma unroll 4
    for (int tt = 0; tt < 128; ++tt)
        a += sc_s[tt] * ep[(size_t)tt * 256];
    atomicAdd(&ctx[b * 256 + tid], a);
}

// ---------------------------------------------------------------------------
__global__ void build_rescat_kernel(const float* __restrict__ pre, const float* __restrict__ x,
                                    float* __restrict__ res)
{
    int idx = blockIdx.x * 256 + threadIdx.x;   // < 128*640
    int m = idx / 640, d = idx - m * 640;
    res[idx] = (d < 128) ? pre[m * 128 + d] : x[m * 512 + d - 128];
}

__global__ void copy_kernel(const float* __restrict__ src, float* __restrict__ dst, int n)
{
    int idx = blockIdx.x * 256 + threadIdx.x;
    if (idx < n) dst[idx] = src[idx];
}

__global__ void stop_kernel(const float* __restrict__ res, const float* __restrict__ sw,
                            const float* __restrict__ sb, float* __restrict__ stop)
{
    int m = blockIdx.x, lane = threadIdx.x;
    float s = 0.f;
    for (int k = lane; k < 640; k += 64) s += res[m * 640 + k] * sw[k];
#pragma unroll
    for (int off = 1; off < 64; off <<= 1) s += __shfl_xor(s, off);
    if (lane == 0) stop[m] = sigm(s + sb[0]);
}

// ---------------------------------------------------------------------------
extern "C" void kernel_launch(void* const* d_in, const int* in_sizes, int n_in,
                              void* d_out, int out_size, void* d_ws, size_t ws_size,
                              hipStream_t stream)
{
    const float* encoder_seq      = (const float*)d_in[0];
    const float* encoder_seq_proj = (const float*)d_in[1];
    const float* prenet_in        = (const float*)d_in[2];
    const float* attn_hidden      = (const float*)d_in[3];
    const float* rnn1_h  = (const float*)d_in[4];
    const float* rnn1_c  = (const float*)d_in[5];
    const float* rnn2_h  = (const float*)d_in[6];
    const float* rnn2_c  = (const float*)d_in[7];
    const float* res_h   = (const float*)d_in[8];
    const float* res_c   = (const float*)d_in[9];
    const float* context_vec = (const float*)d_in[10];
    const float* cumulative  = (const float*)d_in[11];
    const float* attn_prev   = (const float*)d_in[12];
    const float* fc1_w = (const float*)d_in[13];
    const float* fc1_b = (const float*)d_in[14];
    const float* fc2_w = (const float*)d_in[15];
    const float* fc2_b = (const float*)d_in[16];
    const float* gru_wih = (const float*)d_in[17];
    const float* gru_whh = (const float*)d_in[18];
    const float* gru_bih = (const float*)d_in[19];
    const float* gru_bhh = (const float*)d_in[20];
    const float* conv_w = (const float*)d_in[21];
    const float* L_w = (const float*)d_in[22];
    const float* L_b = (const float*)d_in[23];
    const float* W_w = (const float*)d_in[24];
    const float* W_b = (const float*)d_in[25];
    const float* v_w = (const float*)d_in[26];
    const float* ri_w = (const float*)d_in[27];
    const float* ri_b = (const float*)d_in[28];
    const float* r1_wih = (const float*)d_in[29];
    const float* r1_whh = (const float*)d_in[30];
    const float* r1_bih = (const float*)d_in[31];
    const float* r1_bhh = (const float*)d_in[32];
    const float* r2_wih = (const float*)d_in[33];
    const float* r2_whh = (const float*)d_in[34];
    const float* r2_bih = (const float*)d_in[35];
    const float* r2_bhh = (const float*)d_in[36];
    const float* res_wih = (const float*)d_in[37];
    const float* res_whh = (const float*)d_in[38];
    const float* res_bih = (const float*)d_in[39];
    const float* res_bhh = (const float*)d_in[40];
    const float* stop_w = (const float*)d_in[41];
    const float* stop_b = (const float*)d_in[42];

    float* ws  = (float*)d_ws;
    float* out = (float*)d_out;

    // workspace offsets (floats)
    const size_t OFF_P    = 0;        // [128,256]
    const size_t OFF_POUT = 32768;    // [128,128]
    const size_t OFF_PQ   = 49152;    // [128,256]
    const size_t OFF_SIG  = 81920;    // [128,1024]
    const size_t OFF_X    = 212992;   // [128,512]
    const size_t OFF_RES  = 278528;   // [128,640]
    const size_t OFF_LWT  = 360448;   // bf16 L_w [256][32] (16 KB in 32 KB slot)
    const size_t OFF_PART = 368640;   // split-K partials (10.5 MB max)
    const size_t OFF_PARTB = OFF_PART + (size_t)8 * 128 * 768;

    // output offsets (floats)
    const size_t O_COND   = 0;
    const size_t O_STOP   = 81920;
    const size_t O_SCORES = 82048;
    const size_t O_ATTNH  = 213120;
    const size_t O_H1     = 245888;
    const size_t O_C1     = 311424;
    const size_t O_H2     = 376960;
    const size_t O_C2     = 442496;
    const size_t O_HS     = 508032;
    const size_t O_CS     = 835712;
    const size_t O_CTX    = 1163392;
    const size_t O_CUM    = 1196160;

    short* lwbf = (short*)(ws + OFF_LWT);
    lw_bf16_kernel<<<32, 256, 0, stream>>>(L_w, lwbf);

    // PreNet fc1: N=256, K=128, KS=4 (KC=32)
    gemm2s_kernel<<<8 * 4, 256, 0, stream>>>(prenet_in, 128, fc1_w, 128,
                                             nullptr, 0, nullptr, 0,
                                             ws + OFF_PART, 256, 4, 32);
    reduce_act_kernel<<<128, 256, 0, stream>>>(ws + OFF_PART, 4, 128 * 256, fc1_b,
                                               ws + OFF_P, 256, 1);
    // PreNet fc2: N=128, K=256, KS=8 (KC=32)
    gemm2s_kernel<<<4 * 8, 256, 0, stream>>>(ws + OFF_P, 256, fc2_w, 256,
                                             nullptr, 0, nullptr, 0,
                                             ws + OFF_PART, 128, 8, 32);
    reduce_act_kernel<<<64, 256, 0, stream>>>(ws + OFF_PART, 8, 128 * 128, fc2_b,
                                              ws + OFF_POUT, 128, 1);

    // GRU gi: N=768, K=256+128, KS=8 (KC=48);  gh: N=768, K=256, KS=8 (KC=32)
    gemm2s_kernel<<<24 * 8, 256, 0, stream>>>(context_vec, 256, gru_wih, 384,
                                              ws + OFF_POUT, 128, gru_wih + 256, 384,
                                              ws + OFF_PART, 768, 8, 48);
    gemm2s_kernel<<<24 * 8, 256, 0, stream>>>(attn_hidden, 256, gru_whh, 256,
                                              nullptr, 0, nullptr, 0,
                                              ws + OFF_PARTB, 768, 8, 32);
    gru_gate_kernel<<<128, 256, 0, stream>>>(ws + OFF_PART, 8, ws + OFF_PARTB, 8,
                                             gru_bih, gru_bhh, attn_hidden, out + O_ATTNH);

    // pq: N=256, K=256, KS=8 (KC=32)
    gemm2s_kernel<<<8 * 8, 256, 0, stream>>>(out + O_ATTNH, 256, W_w, 256,
                                             nullptr, 0, nullptr, 0,
                                             ws + OFF_PART, 256, 8, 32);
    reduce_act_kernel<<<128, 256, 0, stream>>>(ws + OFF_PART, 8, 128 * 256, W_b,
                                               ws + OFF_PQ, 256, 0);

    attn_u_kernel<<<2048, 256, 0, stream>>>(encoder_seq_proj, ws + OFF_PQ, lwbf,
                                            L_b, v_w, conv_w, cumulative, attn_prev,
                                            ws + OFF_SIG);
    attn_norm_kernel<<<128, 256, 0, stream>>>(ws + OFF_SIG, cumulative,
                                              out + O_SCORES, out + O_CUM, out + O_CTX);
    attn_ctx_kernel<<<1024, 256, 0, stream>>>(out + O_SCORES, encoder_seq, out + O_CTX);

    // x = [context | attn_h] @ ri_w^T + ri_b : N=512, K=512, KS=8 (KC=64)
    gemm2s_kernel<<<16 * 8, 256, 0, stream>>>(out + O_CTX, 256, ri_w, 512,
                                              out + O_ATTNH, 256, ri_w + 256, 512,
                                              ws + OFF_PART, 512, 8, 64);
    reduce_act_kernel<<<256, 256, 0, stream>>>(ws + OFF_PART, 8, 128 * 512, ri_b,
                                               ws + OFF_X, 512, 0);

    // LSTM 1: N=2048, K=1024, KS=8 (KC=128)
    gemm2s_kernel<<<64 * 8, 256, 0, stream>>>(ws + OFF_X, 512, r1_wih, 512,
                                              rnn1_h, 512, r1_whh, 512,
                                              ws + OFF_PART, 2048, 8, 128);
    lstm_gate_kernel<<<dim3(2, 128), 256, 0, stream>>>(ws + OFF_PART, 8, r1_bih, r1_bhh,
                                                       rnn1_c, out + O_H1, out + O_C1,
                                                       ws + OFF_X, 512);
    // LSTM 2
    gemm2s_kernel<<<64 * 8, 256, 0, stream>>>(ws + OFF_X, 512, r2_wih, 512,
                                              rnn2_h, 512, r2_whh, 512,
                                              ws + OFF_PART, 2048, 8, 128);
    lstm_gate_kernel<<<dim3(2, 128), 256, 0, stream>>>(ws + OFF_PART, 8, r2_bih, r2_bhh,
                                                       rnn2_c, out + O_H2, out + O_C2,
                                                       ws + OFF_X, 512);

    build_rescat_kernel<<<320, 256, 0, stream>>>(prenet_in, ws + OFF_X, ws + OFF_RES);

    // Residual stack: N=2560, K=1280, KS=8 (KC=160)
    for (int i = 0; i < 4; ++i) {
        const float* wih = res_wih + (size_t)i * 2560 * 640;
        const float* whh = res_whh + (size_t)i * 2560 * 640;
        gemm2s_kernel<<<80 * 8, 256, 0, stream>>>(ws + OFF_RES, 640, wih, 640,
                                                  res_h + (size_t)i * 81920, 640, whh, 640,
                                                  ws + OFF_PART, 2560, 8, 160);
        lstm_gate_kernel<<<dim3(3, 128), 256, 0, stream>>>(ws + OFF_PART, 8,
                                                           res_bih + (size_t)i * 2560,
                                                           res_bhh + (size_t)i * 2560,
                                                           res_c + (size_t)i * 81920,
                                                           out + O_HS + (size_t)i * 81920,
                                                           out + O_CS + (size_t)i * 81920,
                                                           ws + OFF_RES, 640);
    }

    copy_kernel<<<320, 256, 0, stream>>>(ws + OFF_RES, out + O_COND, 128 * 640);
    stop_kernel<<<128, 64, 0, stream>>>(ws + OFF_RES, stop_w, stop_b, out + O_STOP);
}